// Round 5
// baseline (652.675 us; speedup 1.0000x reference)
//
#include <hip/hip_runtime.h>
#include <hip/hip_bf16.h>

#define N_NODES 50000
#define N_EDGES 1600000
#define IN_DIM 1024
#define HID 128
#define AGG_WAVES 6144          // 1536 blocks x 4 waves = 24 waves/CU at launch_bounds(256,6)

typedef __bf16 bf16x8 __attribute__((ext_vector_type(8)));
typedef float f32x4 __attribute__((ext_vector_type(4)));
typedef __bf16 bf16x4 __attribute__((ext_vector_type(4)));

// bf16-pair (packed in uint) -> 2 floats (features 2l = low, 2l+1 = high)
__device__ __forceinline__ float2 bf2f(unsigned u) {
    return make_float2(__uint_as_float(u << 16), __uint_as_float(u & 0xffff0000u));
}
__device__ __forceinline__ float lrelu(float v) { return v > 0.f ? v : 0.2f * v; }
// fp16 bits (in low 16 of arg) -> float
__device__ __forceinline__ float f16tof(unsigned bits) {
    return (float)__builtin_bit_cast(_Float16, (unsigned short)bits);
}

// ---------------------------------------------------------------- prep: zero deg/out + W^T->bf16
__global__ void prep_kernel(const float* __restrict__ W, __bf16* __restrict__ wt,
                            int* __restrict__ deg, float* __restrict__ out, int out_n) {
    int i = blockIdx.x * 256 + threadIdx.x;       // grid covers 131072
    if (i < N_NODES) deg[i] = 0;
    if (i < out_n) out[i] = 0.0f;
    if (i < HID * IN_DIM) {
        int n = i >> 10, k = i & 1023;
        wt[i] = (__bf16)W[(size_t)k * HID + n];
    }
}

// ---------------------------------------------------------------- GEMM h = x @ W (bf16 MFMA)
// NO-LDS DIRECT GEMM. Rationale (Common-mistake #7: never LDS-stage data that
// cache-fits): W^T is 256KB -> L2-resident per XCD and reused by every wave;
// x is read exactly once (zero reuse). The old reg->LDS->reg round trip + 2
// barriers per K-step bought nothing. Each wave owns 16 output rows; per
// K-step (BK=32) it loads A-frag straight from x (2x float4 -> bf16 in reg)
// and the 8 B-frags straight from wt (8x dwordx4, L2-hit), double-buffered in
// registers one K-step ahead. Zero LDS, zero barriers. Fragment math identical
// to the LDS version (af = x[row0+lm][k0+q8..+8), bfr = wt[ct*16+lm][same]).
__global__ __launch_bounds__(256) void gemm_kernel(const float* __restrict__ x,
                                                   const __bf16* __restrict__ wt,
                                                   __bf16* __restrict__ h2,
                                                   const float* __restrict__ att_s,
                                                   const float* __restrict__ att_d,
                                                   float* __restrict__ o_as,
                                                   float* __restrict__ o_ad,
                                                   float* __restrict__ o_ps) {
    const int t = threadIdx.x;
    const int wid = t >> 6, lane = t & 63;
    const int lm = lane & 15, q8 = (lane >> 4) * 8;
    const int row0 = (blockIdx.x * 4 + wid) * 16;   // wave's 16-row tile
    const int gr = row0 + lm;                       // this lane's A row
    const bool arow_ok = (gr < N_NODES);
    const float* __restrict__ xrow = x + (size_t)gr * IN_DIM + q8;
    const __bf16* __restrict__ wrow = wt + (size_t)lm * IN_DIM + q8;

    auto load_a = [&](int k0, float4& A0, float4& A1) {
        if (arow_ok) {
            A0 = *(const float4*)(xrow + k0);
            A1 = *(const float4*)(xrow + k0 + 4);
        } else {
            A0 = make_float4(0.f, 0.f, 0.f, 0.f);
            A1 = A0;
        }
    };
    auto load_b = [&](int k0, uint4* B) {
#pragma unroll
        for (int ct = 0; ct < 8; ++ct)
            B[ct] = *(const uint4*)(wrow + (size_t)ct * 16 * IN_DIM + k0);
    };
    auto cvt_a = [&](const float4& A0, const float4& A1) {
        bf16x8 af;
        af[0] = (__bf16)A0.x; af[1] = (__bf16)A0.y;
        af[2] = (__bf16)A0.z; af[3] = (__bf16)A0.w;
        af[4] = (__bf16)A1.x; af[5] = (__bf16)A1.y;
        af[6] = (__bf16)A1.z; af[7] = (__bf16)A1.w;
        return af;
    };

    f32x4 acc[8] = {};
    float4 A0a, A1a, A0b, A1b;
    uint4 Ba[8], Bb[8];
    load_a(0, A0a, A1a);
    load_b(0, Ba);
    // manually 2-unrolled so both prefetch buffers are statically named (rule #20)
    for (int it = 0; it < 32; it += 2) {
        if (it + 1 < 32) { load_a((it + 1) * 32, A0b, A1b); load_b((it + 1) * 32, Bb); }
        {
            bf16x8 af = cvt_a(A0a, A1a);
#pragma unroll
            for (int ct = 0; ct < 8; ++ct)
                acc[ct] = __builtin_amdgcn_mfma_f32_16x16x32_bf16(
                    af, *(const bf16x8*)&Ba[ct], acc[ct], 0, 0, 0);
        }
        if (it + 2 < 32) { load_a((it + 2) * 32, A0a, A1a); load_b((it + 2) * 32, Ba); }
        if (it + 1 < 32) {
            bf16x8 af = cvt_a(A0b, A1b);
#pragma unroll
            for (int ct = 0; ct < 8; ++ct)
                acc[ct] = __builtin_amdgcn_mfma_f32_16x16x32_bf16(
                    af, *(const bf16x8*)&Bb[ct], acc[ct], 0, 0, 0);
        }
    }
    // epilogue: C/D layout col=lane&15, row=(lane>>4)*4+reg ; fused att dots
    const int quad = lane >> 4;
    float attsf[8], attdf[8];
#pragma unroll
    for (int ct = 0; ct < 8; ++ct) {
        attsf[ct] = att_s[ct * 16 + lm];
        attdf[ct] = att_d[ct * 16 + lm];
    }
#pragma unroll
    for (int reg = 0; reg < 4; ++reg) {
        int row = row0 + quad * 4 + reg;
        float ps = 0.f, pd = 0.f;
#pragma unroll
        for (int ct = 0; ct < 8; ++ct) {
            float v = acc[ct][reg];
            ps = fmaf(v, attsf[ct], ps);
            pd = fmaf(v, attdf[ct], pd);
        }
#pragma unroll
        for (int o = 8; o; o >>= 1) {
            ps += __shfl_xor(ps, o);
            pd += __shfl_xor(pd, o);
        }
        if (row < N_NODES) {
            if (lm == 0) {
                o_as[row] = ps; o_ad[row] = pd;
                o_ps[row] = __expf(lrelu(ps + pd));   // self-loop weight, precomputed
            }
#pragma unroll
            for (int ct = 0; ct < 8; ++ct)
                h2[(size_t)row * HID + ct * 16 + lm] = (__bf16)acc[ct][reg];
        }
    }
}

// ---------------------------------------------------------------- CSR build
__global__ void hist_kernel(const int* __restrict__ ei, int* __restrict__ deg) {
    int e = blockIdx.x * 256 + threadIdx.x;
    if (e < N_EDGES) atomicAdd(&deg[ei[N_EDGES + e]], 1);
}

__global__ void scan1_kernel(const int* __restrict__ deg, int* __restrict__ bsum) {
    int b = blockIdx.x, t = threadIdx.x;
    int base = b * 1024 + t * 4;
    int s = 0;
#pragma unroll
    for (int j = 0; j < 4; ++j) {
        int idx = base + j;
        if (idx < N_NODES) s += deg[idx];
    }
    for (int o = 32; o; o >>= 1) s += __shfl_xor(s, o);
    __shared__ int wsum[4];
    int lane = t & 63, w = t >> 6;
    if (lane == 0) wsum[w] = s;
    __syncthreads();
    if (t == 0) bsum[b] = wsum[0] + wsum[1] + wsum[2] + wsum[3];
}

__global__ void scan2_kernel(const int* __restrict__ bsum, int* __restrict__ boff,
                             int* __restrict__ rowstart, int nb) {
    if (threadIdx.x == 0 && blockIdx.x == 0) {
        int run = 0;
        for (int i = 0; i < nb; ++i) { boff[i] = run; run += bsum[i]; }
        rowstart[N_NODES] = run;
    }
}

// also materializes cursor = rowstart copy for scatter's atomic slot claim
__global__ void scan3_kernel(const int* __restrict__ deg, const int* __restrict__ boff,
                             int* __restrict__ rowstart, int* __restrict__ cursor) {
    int b = blockIdx.x, t = threadIdx.x;
    int base = b * 1024 + t * 4;
    int v[4]; int s = 0;
#pragma unroll
    for (int j = 0; j < 4; ++j) {
        int idx = base + j;
        v[j] = (idx < N_NODES) ? deg[idx] : 0;
        s += v[j];
    }
    int lane = t & 63, w = t >> 6;
    int inc = s;
    for (int o = 1; o < 64; o <<= 1) {
        int u = __shfl_up(inc, o);
        if (lane >= o) inc += u;
    }
    __shared__ int wt[4];
    if (lane == 63) wt[w] = inc;
    __syncthreads();
    int woff = 0;
    for (int i = 0; i < w; ++i) woff += wt[i];
    int run = woff + inc - s + boff[b];
#pragma unroll
    for (int j = 0; j < 4; ++j) {
        int idx = base + j;
        if (idx < N_NODES) {
            rowstart[idx] = run;
            cursor[idx] = run;
            run += v[j];
        }
    }
}

// scatter: slot via atomic cursor. PACKED payload: u16 src | fp16 pe (4B/edge).
// src < 65536 OK (N=50000); pe in [~e^-1, ~e^3], well inside fp16; 2^-11 rel
// error is ~10x below the bf16 noise floor.
__global__ void scatter_kernel(const int* __restrict__ ei, int* __restrict__ cursor,
                               unsigned* __restrict__ csrp, const float* __restrict__ a_src,
                               const float* __restrict__ a_dst) {
    int e = blockIdx.x * 256 + threadIdx.x;
    if (e >= N_EDGES) return;
    int s = ei[e], d = ei[N_EDGES + e];
    int slot = atomicAdd(&cursor[d], 1);
    float pe = __expf(lrelu(a_src[s] + a_dst[d]));
    unsigned short hb = __builtin_bit_cast(unsigned short, (_Float16)pe);
    csrp[slot] = (unsigned)s | ((unsigned)hb << 16);
}

// ---------------------------------------------------------------- aggregate+pool
// R0's measured-best shape at its measured-best register budget: lane owns
// features {2l,2l+1}; 64-edge chunk per lane; 16-deep register batch of
// shfl-broadcast packed (src|pe) -> 16 independent row-gathers in flight.
// launch_bounds(256,6): VGPR cap 85 (bounds(256,8) spilled -- R3 lesson).
// Denominator accumulated redundantly per-lane from the broadcast pe.
__global__ __launch_bounds__(256, 6) void aggregate_kernel(
    const unsigned* __restrict__ h2u, const float* __restrict__ pself_a,
    const int* __restrict__ rowstart, const unsigned* __restrict__ csrp,
    const float* __restrict__ bias, const int* __restrict__ batch,
    float* __restrict__ out) {
    const int wid = threadIdx.x >> 6, lane = threadIdx.x & 63;
    const int w = blockIdx.x * 4 + wid;
    const int q = N_NODES / AGG_WAVES;
    const int r = N_NODES - q * AGG_WAVES;
    int n0 = w * q + (w < r ? w : r);
    int n1 = n0 + q + (w < r ? 1 : 0);
    const float b0 = bias[2 * lane], b1 = bias[2 * lane + 1];

    int gcur = -1;
    float m0 = 0.f, m1 = 0.f;
    for (int n = n0; n < n1; ++n) {
        int rs = rowstart[n], re = rowstart[n + 1];
        float psf = pself_a[n];
        float2 hv = bf2f(h2u[((unsigned)n << 6) | (unsigned)lane]);
        float denom = psf;
        float2 acc = make_float2(psf * hv.x, psf * hv.y);
        for (int base = rs; base < re; base += 64) {
            int cnt = re - base; if (cnt > 64) cnt = 64;
            unsigned sp = 0u;                 // src=0, pe=0 for invalid lanes
            if (base + lane < re) sp = csrp[base + lane];
            for (int e = 0; e < cnt; e += 16) {
                unsigned bb[16], uu[16];
#pragma unroll
                for (int i = 0; i < 16; ++i) {
                    bb[i] = (unsigned)__shfl((int)sp, e + i);
                    uu[i] = h2u[((bb[i] & 0xffffu) << 6) | (unsigned)lane];
                }
#pragma unroll
                for (int i = 0; i < 16; ++i) {
                    float2 g = bf2f(uu[i]);
                    float p = f16tof(bb[i] >> 16);
                    acc.x = fmaf(p, g.x, acc.x);
                    acc.y = fmaf(p, g.y, acc.y);
                    denom += p;               // every lane sums every pe: no shfl reduce
                }
            }
        }
        float inv = 1.0f / denom;
        float o0 = fmaxf(fmaf(acc.x, inv, b0), 0.0f);
        float o1 = fmaxf(fmaf(acc.y, inv, b1), 0.0f);
        int g = batch[n];
        if (g != gcur) {
            if (gcur >= 0) {
                unsigned* outp = (unsigned*)(out + (size_t)gcur * HID);
                atomicMax(&outp[2 * lane], __float_as_uint(m0));
                atomicMax(&outp[2 * lane + 1], __float_as_uint(m1));
            }
            gcur = g; m0 = o0; m1 = o1;
        } else {
            m0 = fmaxf(m0, o0); m1 = fmaxf(m1, o1);
        }
    }
    if (gcur >= 0) {
        unsigned* outp = (unsigned*)(out + (size_t)gcur * HID);
        atomicMax(&outp[2 * lane], __float_as_uint(m0));
        atomicMax(&outp[2 * lane + 1], __float_as_uint(m1));
    }
}

// ---------------------------------------------------------------- launch
extern "C" void kernel_launch(void* const* d_in, const int* in_sizes, int n_in,
                              void* d_out, int out_size, void* d_ws, size_t ws_size,
                              hipStream_t stream) {
    const float* x     = (const float*)d_in[0];
    const float* W     = (const float*)d_in[1];
    const float* att_s = (const float*)d_in[2];
    const float* att_d = (const float*)d_in[3];
    const float* bias  = (const float*)d_in[4];
    const int*   ei    = (const int*)d_in[5];
    const int*   batch = (const int*)d_in[6];
    float*       out   = (float*)d_out;

    char* ws = (char*)d_ws;
    size_t off = 0;
    auto alloc = [&](size_t bytes) -> void* {
        void* p = ws + off;
        off += (bytes + 255) & ~(size_t)255;
        return p;
    };
    const int NB = (N_NODES + 1023) / 1024;   // 49
    __bf16*   h2       = (__bf16*)alloc((size_t)N_NODES * HID * 2);
    __bf16*   wt       = (__bf16*)alloc((size_t)HID * IN_DIM * 2);
    float*    a_src    = (float*)alloc((size_t)N_NODES * 4);
    float*    a_dst    = (float*)alloc((size_t)N_NODES * 4);
    float*    pself    = (float*)alloc((size_t)N_NODES * 4);
    int*      deg      = (int*)alloc((size_t)N_NODES * 4);
    int*      rowstart = (int*)alloc((size_t)(N_NODES + 1) * 4);
    int*      cursor   = (int*)alloc((size_t)N_NODES * 4);
    int*      bsum     = (int*)alloc((size_t)NB * 4);
    int*      boff     = (int*)alloc((size_t)NB * 4);
    unsigned* csrp     = (unsigned*)alloc((size_t)N_EDGES * 4);
    (void)ws_size; (void)in_sizes; (void)n_in;

    hipLaunchKernelGGL(prep_kernel, dim3(512), dim3(256), 0, stream,
                       W, wt, deg, out, out_size);
    hipLaunchKernelGGL(gemm_kernel, dim3((N_NODES + 63) / 64), dim3(256), 0, stream,
                       x, wt, h2, att_s, att_d, a_src, a_dst, pself);
    hipLaunchKernelGGL(hist_kernel, dim3((N_EDGES + 255) / 256), dim3(256), 0, stream,
                       ei, deg);
    hipLaunchKernelGGL(scan1_kernel, dim3(NB), dim3(256), 0, stream, deg, bsum);
    hipLaunchKernelGGL(scan2_kernel, dim3(1), dim3(64), 0, stream, bsum, boff, rowstart, NB);
    hipLaunchKernelGGL(scan3_kernel, dim3(NB), dim3(256), 0, stream, deg, boff, rowstart, cursor);
    hipLaunchKernelGGL(scatter_kernel, dim3((N_EDGES + 255) / 256), dim3(256), 0, stream,
                       ei, cursor, csrp, a_src, a_dst);
    hipLaunchKernelGGL(aggregate_kernel, dim3(AGG_WAVES / 4), dim3(256), 0, stream,
                       (const unsigned*)h2, pself, rowstart, csrp, bias, batch, out);
}

// Round 6
// 503.260 us; speedup vs baseline: 1.2969x; 1.2969x over previous
//
#include <hip/hip_runtime.h>
#include <hip/hip_bf16.h>

#define N_NODES 50000
#define N_EDGES 1600000
#define IN_DIM 1024
#define HID 128
#define AGG_WAVES 6144          // 1536 blocks x 4 waves = 24 waves/CU at launch_bounds(256,6)

typedef __bf16 bf16x8 __attribute__((ext_vector_type(8)));
typedef float f32x4 __attribute__((ext_vector_type(4)));
typedef __bf16 bf16x4 __attribute__((ext_vector_type(4)));

// bf16-pair (packed in uint) -> 2 floats (features 2l = low, 2l+1 = high)
__device__ __forceinline__ float2 bf2f(unsigned u) {
    return make_float2(__uint_as_float(u << 16), __uint_as_float(u & 0xffff0000u));
}
__device__ __forceinline__ float lrelu(float v) { return v > 0.f ? v : 0.2f * v; }
// fp16 bits (in low 16 of arg) -> float
__device__ __forceinline__ float f16tof(unsigned bits) {
    return (float)__builtin_bit_cast(_Float16, (unsigned short)bits);
}

// ---------------------------------------------------------------- prep: zero deg/out + W^T->bf16
__global__ void prep_kernel(const float* __restrict__ W, __bf16* __restrict__ wt,
                            int* __restrict__ deg, float* __restrict__ out, int out_n) {
    int i = blockIdx.x * 256 + threadIdx.x;       // grid covers 131072
    if (i < N_NODES) deg[i] = 0;
    if (i < out_n) out[i] = 0.0f;
    if (i < HID * IN_DIM) {
        int n = i >> 10, k = i & 1023;
        wt[i] = (__bf16)W[(size_t)k * HID + n];
    }
}

// ---------------------------------------------------------------- GEMM h = x @ W (bf16 MFMA)
// BM=64 x BN=128 (full HID), BK=32, 782 blocks. Double-buffered LDS, one barrier
// per k-iter, register prefetch of next tile. (R5's no-LDS variant measured
// 232us at 2% MFMA / 2.8% VALU -- pure load-latency serialization; the LDS
// staging IS the latency-hiding structure. Reverted.)
// NEW: epilogue repacks h2 through the dead LDS buffers (union-aliased) for
// coalesced 8B stores -- R5 counters showed 60MB WRITE_SIZE for a 12.8MB
// output (4.6x amplification from 2B scattered stores).
__global__ __launch_bounds__(256) void gemm_kernel(const float* __restrict__ x,
                                                   const __bf16* __restrict__ wt,
                                                   __bf16* __restrict__ h2,
                                                   const float* __restrict__ att_s,
                                                   const float* __restrict__ att_d,
                                                   float* __restrict__ o_as,
                                                   float* __restrict__ o_ad,
                                                   float* __restrict__ o_ps) {
    __shared__ union {
        struct { __bf16 xa[2][64][40]; __bf16 wb[2][128][40]; } s;   // 30.7 KB
        __bf16 ep[64][132];                                          // 16.9 KB (epilogue)
    } u;
    const int t = threadIdx.x;
    const int m0 = blockIdx.x * 64;
    const int wid = t >> 6, lane = t & 63;
    const int lm = lane & 15, q8 = (lane >> 4) * 8;
    const int rw0 = wid * 16;

    float4 xs_reg[2];
    uint2  ws_reg[4];

    auto stage_regs = [&](int k0) {
#pragma unroll
        for (int l = 0; l < 2; ++l) {
            int f = t + l * 256;
            int row = f >> 3, kq = f & 7;
            int gr = m0 + row;
            float4 v = make_float4(0.f, 0.f, 0.f, 0.f);
            if (gr < N_NODES)
                v = *(const float4*)(x + (size_t)gr * IN_DIM + k0 + kq * 4);
            xs_reg[l] = v;
        }
#pragma unroll
        for (int l = 0; l < 4; ++l) {
            int f = t + l * 256;
            int n = f >> 3, c = f & 7;
            ws_reg[l] = *(const uint2*)(wt + (size_t)n * IN_DIM + k0 + c * 4);
        }
    };
    auto regs_to_lds = [&](int b) {
#pragma unroll
        for (int l = 0; l < 2; ++l) {
            int f = t + l * 256;
            int row = f >> 3, kq = f & 7;
            bf16x4 v;
            v[0] = (__bf16)xs_reg[l].x; v[1] = (__bf16)xs_reg[l].y;
            v[2] = (__bf16)xs_reg[l].z; v[3] = (__bf16)xs_reg[l].w;
            *(bf16x4*)&u.s.xa[b][row][kq * 4] = v;
        }
#pragma unroll
        for (int l = 0; l < 4; ++l) {
            int f = t + l * 256;
            int n = f >> 3, c = f & 7;
            *(uint2*)&u.s.wb[b][n][c * 4] = ws_reg[l];
        }
    };

    f32x4 acc[8] = {};
    stage_regs(0);
    regs_to_lds(0);
    __syncthreads();
    for (int it = 0; it < 32; ++it) {
        const int cur = it & 1;
        if (it + 1 < 32) stage_regs((it + 1) * 32);   // global loads in flight during MFMA
        bf16x8 af = *(const bf16x8*)&u.s.xa[cur][rw0 + lm][q8];
#pragma unroll
        for (int ct = 0; ct < 8; ++ct) {
            bf16x8 bfr = *(const bf16x8*)&u.s.wb[cur][ct * 16 + lm][q8];
            acc[ct] = __builtin_amdgcn_mfma_f32_16x16x32_bf16(af, bfr, acc[ct], 0, 0, 0);
        }
        if (it + 1 < 32) {
            regs_to_lds(cur ^ 1);     // write OTHER buffer: no read-write conflict
            __syncthreads();          // make writes visible for next iter's reads
        }
    }
    // epilogue part 1: fused att dots (C/D layout col=lane&15, row=(lane>>4)*4+reg)
    const int quad = lane >> 4;
    float attsf[8], attdf[8];
#pragma unroll
    for (int ct = 0; ct < 8; ++ct) {
        attsf[ct] = att_s[ct * 16 + lm];
        attdf[ct] = att_d[ct * 16 + lm];
    }
#pragma unroll
    for (int reg = 0; reg < 4; ++reg) {
        int row = m0 + rw0 + quad * 4 + reg;
        float ps = 0.f, pd = 0.f;
#pragma unroll
        for (int ct = 0; ct < 8; ++ct) {
            float v = acc[ct][reg];
            ps = fmaf(v, attsf[ct], ps);
            pd = fmaf(v, attdf[ct], pd);
        }
#pragma unroll
        for (int o = 8; o; o >>= 1) {
            ps += __shfl_xor(ps, o);
            pd += __shfl_xor(pd, o);
        }
        if (row < N_NODES && lm == 0) {
            o_as[row] = ps; o_ad[row] = pd;
            o_ps[row] = __expf(lrelu(ps + pd));   // self-loop weight, precomputed
        }
    }
    // epilogue part 2: h2 via LDS repack -> coalesced 8B stores.
    // ds_write banks: word = 66*row + 8*ct + (lm>>1); quad rows 4 apart ->
    // 264q%32 = 8q bank offset, lm>>1 spans 8 -> 32 banks, 2 lanes each (free).
    __syncthreads();              // all waves done with xa/wb before aliasing
#pragma unroll
    for (int reg = 0; reg < 4; ++reg) {
        int lrow = rw0 + quad * 4 + reg;
#pragma unroll
        for (int ct = 0; ct < 8; ++ct)
            u.ep[lrow][ct * 16 + lm] = (__bf16)acc[ct][reg];
    }
    __syncthreads();
    {
        int lr = t >> 2, qt = t & 3;             // row 0..63, 32-feature quarter
        int grow = m0 + lr;
        if (grow < N_NODES) {
            uint2* dst = (uint2*)(h2 + (size_t)grow * HID + qt * 32);
            const __bf16* srcp = &u.ep[lr][qt * 32];
#pragma unroll
            for (int j = 0; j < 8; ++j)
                dst[j] = *(const uint2*)(srcp + j * 4);
        }
    }
}

// ---------------------------------------------------------------- CSR build
// SINGLE atomic pass over edges (R0 structure restored): hist's atomicAdd also
// records each edge's slot within its dst row (epos); scatter is atomic-free.
// R1-R4's cursor variant ran a SECOND 1.6M-atomic pass in scatter -- the
// persistent ~15us gap vs the 507 baseline.
__global__ void hist_kernel(const int* __restrict__ ei, int* __restrict__ deg,
                            int* __restrict__ epos) {
    int e = blockIdx.x * 256 + threadIdx.x;
    if (e < N_EDGES) epos[e] = atomicAdd(&deg[ei[N_EDGES + e]], 1);
}

__global__ void scan1_kernel(const int* __restrict__ deg, int* __restrict__ bsum) {
    int b = blockIdx.x, t = threadIdx.x;
    int base = b * 1024 + t * 4;
    int s = 0;
#pragma unroll
    for (int j = 0; j < 4; ++j) {
        int idx = base + j;
        if (idx < N_NODES) s += deg[idx];
    }
    for (int o = 32; o; o >>= 1) s += __shfl_xor(s, o);
    __shared__ int wsum[4];
    int lane = t & 63, w = t >> 6;
    if (lane == 0) wsum[w] = s;
    __syncthreads();
    if (t == 0) bsum[b] = wsum[0] + wsum[1] + wsum[2] + wsum[3];
}

__global__ void scan2_kernel(const int* __restrict__ bsum, int* __restrict__ boff,
                             int* __restrict__ rowstart, int nb) {
    if (threadIdx.x == 0 && blockIdx.x == 0) {
        int run = 0;
        for (int i = 0; i < nb; ++i) { boff[i] = run; run += bsum[i]; }
        rowstart[N_NODES] = run;
    }
}

__global__ void scan3_kernel(const int* __restrict__ deg, const int* __restrict__ boff,
                             int* __restrict__ rowstart) {
    int b = blockIdx.x, t = threadIdx.x;
    int base = b * 1024 + t * 4;
    int v[4]; int s = 0;
#pragma unroll
    for (int j = 0; j < 4; ++j) {
        int idx = base + j;
        v[j] = (idx < N_NODES) ? deg[idx] : 0;
        s += v[j];
    }
    int lane = t & 63, w = t >> 6;
    int inc = s;
    for (int o = 1; o < 64; o <<= 1) {
        int u = __shfl_up(inc, o);
        if (lane >= o) inc += u;
    }
    __shared__ int wt[4];
    if (lane == 63) wt[w] = inc;
    __syncthreads();
    int woff = 0;
    for (int i = 0; i < w; ++i) woff += wt[i];
    int run = woff + inc - s + boff[b];
#pragma unroll
    for (int j = 0; j < 4; ++j) {
        int idx = base + j;
        if (idx < N_NODES) {
            rowstart[idx] = run;
            run += v[j];
        }
    }
}

// scatter (atomic-free): slot = rowstart[d] + epos[e]. PACKED payload:
// u16 src | fp16 pe (4B/edge), pe = exp(lrelu(a_src[s]+a_dst[d])) precomputed
// so the hot aggregate loop does zero transcendental work. src < 65536 OK;
// pe in [~e^-1, ~e^3], well inside fp16; 2^-11 rel err << bf16 noise floor.
__global__ void scatter_kernel(const int* __restrict__ ei, const int* __restrict__ rowstart,
                               const int* __restrict__ epos, unsigned* __restrict__ csrp,
                               const float* __restrict__ a_src, const float* __restrict__ a_dst) {
    int e = blockIdx.x * 256 + threadIdx.x;
    if (e >= N_EDGES) return;
    int s = ei[e], d = ei[N_EDGES + e];
    float pe = __expf(lrelu(a_src[s] + a_dst[d]));
    unsigned short hb = __builtin_bit_cast(unsigned short, (_Float16)pe);
    csrp[rowstart[d] + epos[e]] = (unsigned)s | ((unsigned)hb << 16);
}

// ---------------------------------------------------------------- aggregate+pool
// R0's measured-best shape at its measured-best register budget: lane owns
// features {2l,2l+1}; 64-edge chunk per lane; 16-deep register batch of
// shfl-broadcast packed (src|pe) -> 16 independent row-gathers in flight.
// launch_bounds(256,6): VGPR cap 85 (bounds(256,8) spilled -- R3 lesson).
// Denominator accumulated redundantly per-lane from the broadcast pe.
__global__ __launch_bounds__(256, 6) void aggregate_kernel(
    const unsigned* __restrict__ h2u, const float* __restrict__ pself_a,
    const int* __restrict__ rowstart, const unsigned* __restrict__ csrp,
    const float* __restrict__ bias, const int* __restrict__ batch,
    float* __restrict__ out) {
    const int wid = threadIdx.x >> 6, lane = threadIdx.x & 63;
    const int w = blockIdx.x * 4 + wid;
    const int q = N_NODES / AGG_WAVES;
    const int r = N_NODES - q * AGG_WAVES;
    int n0 = w * q + (w < r ? w : r);
    int n1 = n0 + q + (w < r ? 1 : 0);
    const float b0 = bias[2 * lane], b1 = bias[2 * lane + 1];

    int gcur = -1;
    float m0 = 0.f, m1 = 0.f;
    for (int n = n0; n < n1; ++n) {
        int rs = rowstart[n], re = rowstart[n + 1];
        float psf = pself_a[n];
        float2 hv = bf2f(h2u[((unsigned)n << 6) | (unsigned)lane]);
        float denom = psf;
        float2 acc = make_float2(psf * hv.x, psf * hv.y);
        for (int base = rs; base < re; base += 64) {
            int cnt = re - base; if (cnt > 64) cnt = 64;
            unsigned sp = 0u;                 // src=0, pe=0 for invalid lanes
            if (base + lane < re) sp = csrp[base + lane];
            for (int e = 0; e < cnt; e += 16) {
                unsigned bb[16], uu[16];
#pragma unroll
                for (int i = 0; i < 16; ++i) {
                    bb[i] = (unsigned)__shfl((int)sp, e + i);
                    uu[i] = h2u[((bb[i] & 0xffffu) << 6) | (unsigned)lane];
                }
#pragma unroll
                for (int i = 0; i < 16; ++i) {
                    float2 g = bf2f(uu[i]);
                    float p = f16tof(bb[i] >> 16);
                    acc.x = fmaf(p, g.x, acc.x);
                    acc.y = fmaf(p, g.y, acc.y);
                    denom += p;               // every lane sums every pe: no shfl reduce
                }
            }
        }
        float inv = 1.0f / denom;
        float o0 = fmaxf(fmaf(acc.x, inv, b0), 0.0f);
        float o1 = fmaxf(fmaf(acc.y, inv, b1), 0.0f);
        int g = batch[n];
        if (g != gcur) {
            if (gcur >= 0) {
                unsigned* outp = (unsigned*)(out + (size_t)gcur * HID);
                atomicMax(&outp[2 * lane], __float_as_uint(m0));
                atomicMax(&outp[2 * lane + 1], __float_as_uint(m1));
            }
            gcur = g; m0 = o0; m1 = o1;
        } else {
            m0 = fmaxf(m0, o0); m1 = fmaxf(m1, o1);
        }
    }
    if (gcur >= 0) {
        unsigned* outp = (unsigned*)(out + (size_t)gcur * HID);
        atomicMax(&outp[2 * lane], __float_as_uint(m0));
        atomicMax(&outp[2 * lane + 1], __float_as_uint(m1));
    }
}

// ---------------------------------------------------------------- launch
extern "C" void kernel_launch(void* const* d_in, const int* in_sizes, int n_in,
                              void* d_out, int out_size, void* d_ws, size_t ws_size,
                              hipStream_t stream) {
    const float* x     = (const float*)d_in[0];
    const float* W     = (const float*)d_in[1];
    const float* att_s = (const float*)d_in[2];
    const float* att_d = (const float*)d_in[3];
    const float* bias  = (const float*)d_in[4];
    const int*   ei    = (const int*)d_in[5];
    const int*   batch = (const int*)d_in[6];
    float*       out   = (float*)d_out;

    char* ws = (char*)d_ws;
    size_t off = 0;
    auto alloc = [&](size_t bytes) -> void* {
        void* p = ws + off;
        off += (bytes + 255) & ~(size_t)255;
        return p;
    };
    const int NB = (N_NODES + 1023) / 1024;   // 49
    __bf16*   h2       = (__bf16*)alloc((size_t)N_NODES * HID * 2);
    __bf16*   wt       = (__bf16*)alloc((size_t)HID * IN_DIM * 2);
    float*    a_src    = (float*)alloc((size_t)N_NODES * 4);
    float*    a_dst    = (float*)alloc((size_t)N_NODES * 4);
    float*    pself    = (float*)alloc((size_t)N_NODES * 4);
    int*      deg      = (int*)alloc((size_t)N_NODES * 4);
    int*      rowstart = (int*)alloc((size_t)(N_NODES + 1) * 4);
    int*      bsum     = (int*)alloc((size_t)NB * 4);
    int*      boff     = (int*)alloc((size_t)NB * 4);
    int*      epos     = (int*)alloc((size_t)N_EDGES * 4);
    unsigned* csrp     = (unsigned*)alloc((size_t)N_EDGES * 4);
    (void)ws_size; (void)in_sizes; (void)n_in;

    hipLaunchKernelGGL(prep_kernel, dim3(512), dim3(256), 0, stream,
                       W, wt, deg, out, out_size);
    hipLaunchKernelGGL(gemm_kernel, dim3((N_NODES + 63) / 64), dim3(256), 0, stream,
                       x, wt, h2, att_s, att_d, a_src, a_dst, pself);
    hipLaunchKernelGGL(hist_kernel, dim3((N_EDGES + 255) / 256), dim3(256), 0, stream,
                       ei, deg, epos);
    hipLaunchKernelGGL(scan1_kernel, dim3(NB), dim3(256), 0, stream, deg, bsum);
    hipLaunchKernelGGL(scan2_kernel, dim3(1), dim3(64), 0, stream, bsum, boff, rowstart, NB);
    hipLaunchKernelGGL(scan3_kernel, dim3(NB), dim3(256), 0, stream, deg, boff, rowstart);
    hipLaunchKernelGGL(scatter_kernel, dim3((N_EDGES + 255) / 256), dim3(256), 0, stream,
                       ei, rowstart, epos, csrp, a_src, a_dst);
    hipLaunchKernelGGL(aggregate_kernel, dim3(AGG_WAVES / 4), dim3(256), 0, stream,
                       (const unsigned*)h2, pself, rowstart, csrp, bias, batch, out);
}